// Round 1
// baseline (2803.137 us; speedup 1.0000x reference)
//
#include <hip/hip_runtime.h>
#include <hip/hip_bf16.h>
#include <math.h>

#define BATCH   2
#define S_LEN   2048
#define D_MODEL 1024
#define NH      16
#define DHEAD   64

// ---------------------------------------------------------------------------
// Tiled fp32 GEMM: C[M=4096 x N=1024] = A[4096 x 1024] * W[1024 x 1024]
// epilogue 0: scatter to [b,h,s,dh] (projection), epilogue 1: row-major (final)
// ---------------------------------------------------------------------------
__global__ __launch_bounds__(256)
void gemm_tiled(const float* __restrict__ A, const float* __restrict__ W,
                float* __restrict__ dst, int epilogue)
{
    __shared__ float As[64][17];
    __shared__ float Bs[16][64];
    const int tid = threadIdx.x;
    const int tx = tid & 15, ty = tid >> 4;
    const int m0 = blockIdx.y * 64;
    const int n0 = blockIdx.x * 64;
    float acc[4][4] = {};

    for (int k0 = 0; k0 < 1024; k0 += 16) {
        {
            const int colA = tid & 15, rbA = tid >> 4;
#pragma unroll
            for (int r = 0; r < 4; ++r) {
                const int row = rbA + r * 16;
                As[row][colA] = A[(size_t)(m0 + row) * 1024 + k0 + colA];
            }
            const int colB = tid & 63, rbB = tid >> 6;
#pragma unroll
            for (int r = 0; r < 4; ++r) {
                const int row = rbB + r * 4;
                Bs[row][colB] = W[(size_t)(k0 + row) * 1024 + n0 + colB];
            }
        }
        __syncthreads();
#pragma unroll
        for (int kk = 0; kk < 16; ++kk) {
            float a[4], bq[4];
#pragma unroll
            for (int i = 0; i < 4; ++i) a[i] = As[ty * 4 + i][kk];
#pragma unroll
            for (int j = 0; j < 4; ++j) bq[j] = Bs[kk][tx * 4 + j];
#pragma unroll
            for (int i = 0; i < 4; ++i)
#pragma unroll
                for (int j = 0; j < 4; ++j)
                    acc[i][j] += a[i] * bq[j];
        }
        __syncthreads();
    }

#pragma unroll
    for (int i = 0; i < 4; ++i) {
        const int m = m0 + ty * 4 + i;
#pragma unroll
        for (int j = 0; j < 4; ++j) {
            const int n = n0 + tx * 4 + j;
            if (epilogue == 0) {
                const int b = m >> 11, s = m & 2047;
                const int h = n >> 6,  dh = n & 63;
                dst[((size_t)((b * NH + h) * S_LEN) + s) * DHEAD + dh] = acc[i][j];
            } else {
                dst[(size_t)m * 1024 + n] = acc[i][j];
            }
        }
    }
}

// ---------------------------------------------------------------------------
// Flash-style differential attention, causal + ALiBi, dual online softmax,
// fused per-head LayerNorm. One block = 64 q-rows of one (b,h).
// ---------------------------------------------------------------------------
__device__ __forceinline__ float red_max16(float v) {
    v = fmaxf(v, __shfl_xor(v, 1));
    v = fmaxf(v, __shfl_xor(v, 2));
    v = fmaxf(v, __shfl_xor(v, 4));
    v = fmaxf(v, __shfl_xor(v, 8));
    return v;
}
__device__ __forceinline__ float red_sum16(float v) {
    v += __shfl_xor(v, 1);
    v += __shfl_xor(v, 2);
    v += __shfl_xor(v, 4);
    v += __shfl_xor(v, 8);
    return v;
}

__global__ __launch_bounds__(256)
void diff_attn(const float* __restrict__ q0b, const float* __restrict__ q1b,
               const float* __restrict__ k0b, const float* __restrict__ k1b,
               const float* __restrict__ vb,
               const float* __restrict__ l0v, const float* __restrict__ l1v,
               const float* __restrict__ l2v, const float* __restrict__ l3v,
               const float* __restrict__ lnw, const float* __restrict__ lnb,
               float* __restrict__ attn)
{
    __shared__ float Qs0[64][65];
    __shared__ float Qs1[64][65];
    __shared__ float KP0[64][65];   // K0 tile, then reused as P0 tile
    __shared__ float KP1[64][65];   // K1 tile, then reused as P1 tile
    __shared__ float Vs [64][65];

    const int tid = threadIdx.x;
    const int tx = tid & 15, ty = tid >> 4;
    const int qt = blockIdx.x;          // q-tile index, 0..31
    const int bh = blockIdx.y;          // 0..31
    const int b = bh >> 4, h = bh & 15;
    const float scale = 0.125f;         // rsqrt(64)
    const float slope = exp2f(-0.5f * (float)(h + 1));

    // lambda scalar (redundant per-thread; broadcast loads, negligible)
    float d01 = 0.f, d23 = 0.f;
    for (int t = 0; t < DHEAD; ++t) {
        d01 += l0v[t] * l1v[t];
        d23 += l2v[t] * l3v[t];
    }
    const float lamb = (-expf(d01) + 0.8f) + (-expf(d23) + 0.8f);

    const size_t headoff = ((size_t)(b * NH + h)) * S_LEN * DHEAD;
    const float* q0p = q0b + headoff + (size_t)qt * 64 * DHEAD;
    const float* q1p = q1b + headoff + (size_t)qt * 64 * DHEAD;
#pragma unroll
    for (int rep = 0; rep < 16; ++rep) {
        const int idx = rep * 256 + tid;
        const int r = idx >> 6, d = idx & 63;
        Qs0[r][d] = q0p[idx];
        Qs1[r][d] = q1p[idx];
    }

    float o0[4][4] = {}, o1[4][4] = {};
    float m0r[4], m1r[4], l0r[4], l1r[4];
#pragma unroll
    for (int i = 0; i < 4; ++i) { m0r[i] = m1r[i] = -1e30f; l0r[i] = l1r[i] = 0.f; }

    for (int kt = 0; kt <= qt; ++kt) {
        __syncthreads();   // prior PV readers done (also covers Q-store->read)
        {
            const float* kp0 = k0b + headoff + (size_t)kt * 64 * DHEAD;
            const float* kp1 = k1b + headoff + (size_t)kt * 64 * DHEAD;
            const float* vp  = vb  + headoff + (size_t)kt * 64 * DHEAD;
#pragma unroll
            for (int rep = 0; rep < 16; ++rep) {
                const int idx = rep * 256 + tid;
                const int r = idx >> 6, d = idx & 63;
                KP0[r][d] = kp0[idx];
                KP1[r][d] = kp1[idx];
                Vs [r][d] = vp [idx];
            }
        }
        __syncthreads();

        // S = Q @ K^T (both branches)
        float s0[4][4], s1[4][4];
#pragma unroll
        for (int i = 0; i < 4; ++i)
#pragma unroll
            for (int j = 0; j < 4; ++j) { s0[i][j] = 0.f; s1[i][j] = 0.f; }

        for (int d = 0; d < 64; ++d) {
            float a0[4], a1[4], c0[4], c1[4];
#pragma unroll
            for (int i = 0; i < 4; ++i) {
                a0[i] = Qs0[ty * 4 + i][d];
                a1[i] = Qs1[ty * 4 + i][d];
            }
#pragma unroll
            for (int j = 0; j < 4; ++j) {
                c0[j] = KP0[tx * 4 + j][d];
                c1[j] = KP1[tx * 4 + j][d];
            }
#pragma unroll
            for (int i = 0; i < 4; ++i)
#pragma unroll
                for (int j = 0; j < 4; ++j) {
                    s0[i][j] += a0[i] * c0[j];
                    s1[i][j] += a1[i] * c1[j];
                }
        }

        // scale, ALiBi bias, causal mask, online softmax update
#pragma unroll
        for (int i = 0; i < 4; ++i) {
            const int rg = qt * 64 + ty * 4 + i;
            float tm0 = -1e30f, tm1 = -1e30f;
#pragma unroll
            for (int j = 0; j < 4; ++j) {
                const int cg = kt * 64 + tx * 4 + j;
                if (cg > rg) {
                    s0[i][j] = -1e30f;
                    s1[i][j] = -1e30f;
                } else {
                    const float bias = slope * (float)(rg - cg);
                    s0[i][j] = s0[i][j] * scale - bias;
                    s1[i][j] = s1[i][j] * scale - bias;
                }
                tm0 = fmaxf(tm0, s0[i][j]);
                tm1 = fmaxf(tm1, s1[i][j]);
            }
            tm0 = red_max16(tm0);
            tm1 = red_max16(tm1);
            const float mn0 = fmaxf(m0r[i], tm0);
            const float mn1 = fmaxf(m1r[i], tm1);
            const float al0 = expf(m0r[i] - mn0);
            const float al1 = expf(m1r[i] - mn1);
            float ts0 = 0.f, ts1 = 0.f;
#pragma unroll
            for (int j = 0; j < 4; ++j) {
                s0[i][j] = expf(s0[i][j] - mn0);
                s1[i][j] = expf(s1[i][j] - mn1);
                ts0 += s0[i][j];
                ts1 += s1[i][j];
            }
            ts0 = red_sum16(ts0);
            ts1 = red_sum16(ts1);
            l0r[i] = l0r[i] * al0 + ts0;
            l1r[i] = l1r[i] * al1 + ts1;
            m0r[i] = mn0;
            m1r[i] = mn1;
#pragma unroll
            for (int j = 0; j < 4; ++j) { o0[i][j] *= al0; o1[i][j] *= al1; }
        }

        __syncthreads();   // everyone done reading K from KP*
        // store P tiles into KP*
#pragma unroll
        for (int i = 0; i < 4; ++i)
#pragma unroll
            for (int j = 0; j < 4; ++j) {
                KP0[ty * 4 + i][tx * 4 + j] = s0[i][j];
                KP1[ty * 4 + i][tx * 4 + j] = s1[i][j];
            }
        __syncthreads();

        // O += P @ V (both branches)
        for (int c = 0; c < 64; ++c) {
            float vv[4], pa0[4], pa1[4];
#pragma unroll
            for (int j = 0; j < 4; ++j) vv[j] = Vs[c][tx * 4 + j];
#pragma unroll
            for (int i = 0; i < 4; ++i) {
                pa0[i] = KP0[ty * 4 + i][c];
                pa1[i] = KP1[ty * 4 + i][c];
            }
#pragma unroll
            for (int i = 0; i < 4; ++i)
#pragma unroll
                for (int j = 0; j < 4; ++j) {
                    o0[i][j] += pa0[i] * vv[j];
                    o1[i][j] += pa1[i] * vv[j];
                }
        }
    }

    // normalize, differential combine, per-head LayerNorm, write out
#pragma unroll
    for (int i = 0; i < 4; ++i) {
        const float inv0 = 1.f / l0r[i];
        const float inv1 = 1.f / l1r[i];
        float hv[4];
        float ssum = 0.f;
#pragma unroll
        for (int j = 0; j < 4; ++j) {
            hv[j] = o0[i][j] * inv0 - lamb * (o1[i][j] * inv1);
            ssum += hv[j];
        }
        ssum = red_sum16(ssum);
        const float mu = ssum * (1.f / 64.f);
        float vsum = 0.f;
#pragma unroll
        for (int j = 0; j < 4; ++j) { const float dd = hv[j] - mu; vsum += dd * dd; }
        vsum = red_sum16(vsum);
        const float rstd = rsqrtf(vsum * (1.f / 64.f) + 1e-5f);
        const int rg = qt * 64 + ty * 4 + i;
#pragma unroll
        for (int j = 0; j < 4; ++j) {
            const int d = tx * 4 + j;
            const float nv = (hv[j] - mu) * rstd * lnw[h * DHEAD + d] + lnb[h * DHEAD + d];
            attn[((size_t)(b * S_LEN + rg)) * D_MODEL + h * DHEAD + d] = nv;
        }
    }
}

// ---------------------------------------------------------------------------
extern "C" void kernel_launch(void* const* d_in, const int* in_sizes, int n_in,
                              void* d_out, int out_size, void* d_ws, size_t ws_size,
                              hipStream_t stream)
{
    (void)in_sizes; (void)n_in; (void)out_size; (void)ws_size;
    const float* x   = (const float*)d_in[0];
    const float* wq0 = (const float*)d_in[1];
    const float* wq1 = (const float*)d_in[2];
    const float* wk0 = (const float*)d_in[3];
    const float* wk1 = (const float*)d_in[4];
    const float* wv  = (const float*)d_in[5];
    const float* wo  = (const float*)d_in[6];
    const float* l0  = (const float*)d_in[7];
    const float* l1  = (const float*)d_in[8];
    const float* l2  = (const float*)d_in[9];
    const float* l3  = (const float*)d_in[10];
    const float* lnw = (const float*)d_in[11];
    const float* lnb = (const float*)d_in[12];
    float* out = (float*)d_out;
    float* ws  = (float*)d_ws;

    const size_t PER = (size_t)BATCH * NH * S_LEN * DHEAD;   // 4,194,304 floats
    float* q0b = ws + 0 * PER;
    float* q1b = ws + 1 * PER;
    float* k0b = ws + 2 * PER;
    float* k1b = ws + 3 * PER;
    float* vb  = ws + 4 * PER;
    float* at  = ws + 5 * PER;

    dim3 blk(256);
    dim3 gg(16, 64);   // N-tiles x M-tiles
    gemm_tiled<<<gg, blk, 0, stream>>>(x, wq0, q0b, 0);
    gemm_tiled<<<gg, blk, 0, stream>>>(x, wq1, q1b, 0);
    gemm_tiled<<<gg, blk, 0, stream>>>(x, wk0, k0b, 0);
    gemm_tiled<<<gg, blk, 0, stream>>>(x, wk1, k1b, 0);
    gemm_tiled<<<gg, blk, 0, stream>>>(x, wv,  vb,  0);

    dim3 ag(32, 32);   // q-tiles x (b*h)
    diff_attn<<<ag, blk, 0, stream>>>(q0b, q1b, k0b, k1b, vb,
                                      l0, l1, l2, l3, lnw, lnb, at);

    gemm_tiled<<<gg, blk, 0, stream>>>(at, wo, out, 1);
}

// Round 2
// 318.502 us; speedup vs baseline: 8.8010x; 8.8010x over previous
//
#include <hip/hip_runtime.h>
#include <hip/hip_bf16.h>
#include <math.h>

#define S_LEN   2048
#define NH      16
#define DHEAD   64

typedef __attribute__((ext_vector_type(8))) short short8;
typedef __attribute__((ext_vector_type(4))) short short4v;
typedef __attribute__((ext_vector_type(4))) float f32x4;

__device__ __forceinline__ f32x4 mfma16(short8 a, short8 b, f32x4 c) {
    return __builtin_amdgcn_mfma_f32_16x16x32_bf16(a, b, c, 0, 0, 0);
}

__device__ __forceinline__ unsigned short f2bf(float f) {
    unsigned u = __builtin_bit_cast(unsigned, f);
    u = (u + 0x7FFFu + ((u >> 16) & 1u)) >> 16;
    return (unsigned short)u;
}

#define GLL16(gp, lp) __builtin_amdgcn_global_load_lds( \
    (const __attribute__((address_space(1))) void*)(gp), \
    (__attribute__((address_space(3))) void*)(lp), 16, 0, 0)

// ---------------------------------------------------------------------------
// fp32 -> bf16 linear convert (X and attention intermediates are A-operands)
// ---------------------------------------------------------------------------
__global__ __launch_bounds__(256)
void convert_x(const float* __restrict__ x, short* __restrict__ xb)
{
    const int idx = (blockIdx.x * 256 + threadIdx.x) * 4;
    typedef __attribute__((ext_vector_type(4))) float f4;
    f4 v = *(const f4*)&x[idx];
    short4v o;
    o[0] = (short)f2bf(v[0]); o[1] = (short)f2bf(v[1]);
    o[2] = (short)f2bf(v[2]); o[3] = (short)f2bf(v[3]);
    *(short4v*)&xb[idx] = o;
}

// ---------------------------------------------------------------------------
// transpose + convert weights: src fp32 [K=1024][N=1024] -> dst bf16 [N][K]
// z selects one of 6 weight matrices.
// ---------------------------------------------------------------------------
__global__ __launch_bounds__(256)
void transp_w(const float* __restrict__ w0, const float* __restrict__ w1,
              const float* __restrict__ w2, const float* __restrict__ w3,
              const float* __restrict__ w4, const float* __restrict__ w5,
              short* __restrict__ wt)
{
    __shared__ float t[64][65];
    const int z = blockIdx.z;
    const float* src = (z == 0) ? w0 : (z == 1) ? w1 : (z == 2) ? w2
                     : (z == 3) ? w3 : (z == 4) ? w4 : w5;
    short* dst = wt + (size_t)z * 1024 * 1024;
    const int n0 = blockIdx.x * 64, k0 = blockIdx.y * 64;
    const int tid = threadIdx.x;
    const int c = tid & 63, rb = tid >> 6;
#pragma unroll
    for (int rr = 0; rr < 16; ++rr) {
        const int r = rr * 4 + rb;
        t[r][c] = src[(size_t)(k0 + r) * 1024 + n0 + c];
    }
    __syncthreads();
#pragma unroll
    for (int rr = 0; rr < 16; ++rr) {
        const int n = rr * 4 + rb;
        dst[(size_t)(n0 + n) * 1024 + k0 + c] = (short)f2bf(t[c][n]);
    }
}

// ---------------------------------------------------------------------------
// bf16 MFMA GEMM: C[M x N] = A[M][1024] * Bt[N][1024]^T, 128x128 tile, BK=64.
// Both LDS tiles staged via global_load_lds with source-side chunk-XOR swizzle
// (linear LDS dest), read back conflict-free as 16B fragments.
// mode 0: grid.z selects weight/out slot, epilogue scatters bf16 [b,h,s,dh]
// mode 1: fp32 row-major output
// ---------------------------------------------------------------------------
__global__ __launch_bounds__(256)
void gemm128(const short* __restrict__ A, const short* __restrict__ Wt,
             short* __restrict__ outb, float* __restrict__ outf, int mode)
{
    __shared__ short As[128 * 64];
    __shared__ short Bs[128 * 64];
    const int tid = threadIdx.x;
    const int l = tid & 63, w = tid >> 6;
    const int wm = w >> 1, wn = w & 1;
    const int m0 = blockIdx.y * 128;
    const int n0 = blockIdx.x * 128;
    const short* Bt = Wt + (size_t)blockIdx.z * (1024 * 1024);
    const int srow = l >> 3;                  // row within 8-row staging group
    const int schunk = (l & 7) ^ srow;        // swizzled source 16B chunk

    f32x4 acc[4][4];
#pragma unroll
    for (int i = 0; i < 4; ++i)
#pragma unroll
        for (int j = 0; j < 4; ++j)
            acc[i][j] = (f32x4){0.f, 0.f, 0.f, 0.f};

    for (int k0 = 0; k0 < 1024; k0 += 64) {
        __syncthreads();
#pragma unroll
        for (int ii = 0; ii < 4; ++ii) {
            const int i = w * 4 + ii;
            GLL16(A  + (size_t)(m0 + 8 * i + srow) * 1024 + k0 + schunk * 8, &As[i * 512]);
            GLL16(Bt + (size_t)(n0 + 8 * i + srow) * 1024 + k0 + schunk * 8, &Bs[i * 512]);
        }
        __syncthreads();
#pragma unroll
        for (int kh = 0; kh < 2; ++kh) {
            short8 af[4], bfr[4];
#pragma unroll
            for (int ft = 0; ft < 4; ++ft) {
                const int row = wm * 64 + ft * 16 + (l & 15);
                const int ch = (kh * 4 + (l >> 4)) ^ (row & 7);
                af[ft] = *(const short8*)&As[row * 64 + ch * 8];
            }
#pragma unroll
            for (int nt = 0; nt < 4; ++nt) {
                const int row = wn * 64 + nt * 16 + (l & 15);
                const int ch = (kh * 4 + (l >> 4)) ^ (row & 7);
                bfr[nt] = *(const short8*)&Bs[row * 64 + ch * 8];
            }
#pragma unroll
            for (int i = 0; i < 4; ++i)
#pragma unroll
                for (int j = 0; j < 4; ++j)
                    acc[i][j] = mfma16(af[i], bfr[j], acc[i][j]);
        }
    }

#pragma unroll
    for (int i = 0; i < 4; ++i)
#pragma unroll
        for (int j = 0; j < 4; ++j)
#pragma unroll
            for (int r = 0; r < 4; ++r) {
                const int m = m0 + wm * 64 + i * 16 + (l >> 4) * 4 + r;
                const int n = n0 + wn * 64 + j * 16 + (l & 15);
                const float v = acc[i][j][r];
                if (mode == 0) {
                    const int b = m >> 11, s = m & 2047;
                    const int h = n >> 6, dh = n & 63;
                    outb[(size_t)blockIdx.z * (4u * 1024 * 1024)
                         + (((size_t)(b * NH + h)) * S_LEN + s) * DHEAD + dh] = (short)f2bf(v);
                } else {
                    outf[(size_t)m * 1024 + n] = v;
                }
            }
}

// ---------------------------------------------------------------------------
// MFMA flash differential attention. Block = 256 thr (4 waves), 64 q-rows,
// KV tiles of 64. Swapped QK^T (S^T = mfma(K,Q)) so each lane owns one q-row:
// row softmax = 2 shuffles; P packs as contiguous ds_write_b64. V staged
// transposed so PV B-operand is a contiguous 16B read. Fused LN epilogue.
// ---------------------------------------------------------------------------
__global__ __launch_bounds__(256)
void diff_attn_mfma(const short* __restrict__ pbuf,
                    const float* __restrict__ l0v, const float* __restrict__ l1v,
                    const float* __restrict__ l2v, const float* __restrict__ l3v,
                    const float* __restrict__ lnw, const float* __restrict__ lnb,
                    short* __restrict__ attnout)
{
    __shared__ short K0s[64 * 64];
    __shared__ short K1s[64 * 64];
    __shared__ short Vts[64 * 64];
    __shared__ short Ps[2][4][16 * 64];

    const int tid = threadIdx.x;
    const int l = tid & 63, w = tid >> 6;
    const int g = l >> 4, q16 = l & 15;
    const int qt = (int)gridDim.x - 1 - (int)blockIdx.x;   // heavy tiles first
    const int bh = blockIdx.y;
    const int b = bh >> 4, h = bh & 15;
    const size_t MAT = (size_t)32 * S_LEN * DHEAD;
    const size_t hoff = (size_t)bh * S_LEN * DHEAD;
    const short* q0g = pbuf + 0 * MAT + hoff;
    const short* q1g = pbuf + 1 * MAT + hoff;
    const short* k0g = pbuf + 2 * MAT + hoff;
    const short* k1g = pbuf + 3 * MAT + hoff;
    const short* vg  = pbuf + 4 * MAT + hoff;

    const float scale = 0.125f;
    const float slope = exp2f(-0.5f * (float)(h + 1));
    float d01 = 0.f, d23 = 0.f;
    for (int t = 0; t < DHEAD; ++t) { d01 += l0v[t] * l1v[t]; d23 += l2v[t] * l3v[t]; }
    const float lamb = (-__expf(d01) + 0.8f) + (-__expf(d23) + 0.8f);

    const int rg = qt * 64 + w * 16 + q16;   // this lane's q-row (global)
    short8 q0f[2], q1f[2];
#pragma unroll
    for (int kh = 0; kh < 2; ++kh) {
        q0f[kh] = *(const short8*)&q0g[(size_t)rg * DHEAD + kh * 32 + g * 8];
        q1f[kh] = *(const short8*)&q1g[(size_t)rg * DHEAD + kh * 32 + g * 8];
    }

    f32x4 o0[4], o1[4];
#pragma unroll
    for (int c = 0; c < 4; ++c) { o0[c] = (f32x4){0.f,0.f,0.f,0.f}; o1[c] = (f32x4){0.f,0.f,0.f,0.f}; }
    float m0r = -1e30f, m1r = -1e30f, l0r = 0.f, l1r = 0.f;

    const int srow = l >> 3;
    const int schunk = (l & 7) ^ srow;

    for (int kt = 0; kt <= qt; ++kt) {
        __syncthreads();   // previous iteration's LDS readers done
        // --- stage K0, K1 (global_load_lds, swizzled source) ---
#pragma unroll
        for (int ii = 0; ii < 2; ++ii) {
            const int i = w * 2 + ii;
            GLL16(k0g + (size_t)(kt * 64 + 8 * i + srow) * DHEAD + schunk * 8, &K0s[i * 512]);
            GLL16(k1g + (size_t)(kt * 64 + 8 * i + srow) * DHEAD + schunk * 8, &K1s[i * 512]);
        }
        // --- stage V transposed: wave w owns d-rows [w*16, w*16+16) ---
        {
            const short* vp = vg + (size_t)(kt * 64 + l) * DHEAD + w * 16;
            short8 va = *(const short8*)vp;
            short8 vb2 = *(const short8*)(vp + 8);
#pragma unroll
            for (int e = 0; e < 16; ++e) {
                const short val = (e < 8) ? va[e] : vb2[e - 8];
                const int drow = w * 16 + e;
                const int csw = (l >> 3) ^ (drow & 7);
                Vts[drow * 64 + csw * 8 + (l & 7)] = val;
            }
        }
        __syncthreads();

        // --- S^T = K @ Q^T: lane holds S[q=q16][kv = c*16 + g*4 + j] ---
        f32x4 s0[4], s1[4];
#pragma unroll
        for (int c = 0; c < 4; ++c) { s0[c] = (f32x4){0.f,0.f,0.f,0.f}; s1[c] = (f32x4){0.f,0.f,0.f,0.f}; }
#pragma unroll
        for (int c = 0; c < 4; ++c)
#pragma unroll
            for (int kh = 0; kh < 2; ++kh) {
                const int row = c * 16 + q16;
                const int ch = (kh * 4 + g) ^ (row & 7);
                const short8 k0fr = *(const short8*)&K0s[row * 64 + ch * 8];
                const short8 k1fr = *(const short8*)&K1s[row * 64 + ch * 8];
                s0[c] = mfma16(k0fr, q0f[kh], s0[c]);
                s1[c] = mfma16(k1fr, q1f[kh], s1[c]);
            }

        // --- scale + ALiBi + causal mask, dual online softmax ---
        float pm0 = -1e30f, pm1 = -1e30f;
#pragma unroll
        for (int c = 0; c < 4; ++c)
#pragma unroll
            for (int j = 0; j < 4; ++j) {
                const int cg = kt * 64 + c * 16 + g * 4 + j;
                if (cg > rg) { s0[c][j] = -1e30f; s1[c][j] = -1e30f; }
                else {
                    const float bias = slope * (float)(rg - cg);
                    s0[c][j] = s0[c][j] * scale - bias;
                    s1[c][j] = s1[c][j] * scale - bias;
                }
                pm0 = fmaxf(pm0, s0[c][j]);
                pm1 = fmaxf(pm1, s1[c][j]);
            }
        pm0 = fmaxf(pm0, __shfl_xor(pm0, 16)); pm0 = fmaxf(pm0, __shfl_xor(pm0, 32));
        pm1 = fmaxf(pm1, __shfl_xor(pm1, 16)); pm1 = fmaxf(pm1, __shfl_xor(pm1, 32));
        const float mn0 = fmaxf(m0r, pm0);
        const float mn1 = fmaxf(m1r, pm1);
        const float al0 = __expf(m0r - mn0);
        const float al1 = __expf(m1r - mn1);
        float rs0 = 0.f, rs1 = 0.f;
#pragma unroll
        for (int c = 0; c < 4; ++c) {
            short4v pk0, pk1;
#pragma unroll
            for (int j = 0; j < 4; ++j) {
                const float p0 = __expf(s0[c][j] - mn0);
                const float p1 = __expf(s1[c][j] - mn1);
                rs0 += p0; rs1 += p1;
                pk0[j] = (short)f2bf(p0);
                pk1[j] = (short)f2bf(p1);
            }
            const int colb = c * 16 + g * 4;
            const int csw = (colb >> 3) ^ (q16 & 7);
            const int off = q16 * 128 + csw * 16 + (colb & 7) * 2;   // bytes
            *(short4v*)((char*)&Ps[0][w][0] + off) = pk0;
            *(short4v*)((char*)&Ps[1][w][0] + off) = pk1;
        }
        rs0 += __shfl_xor(rs0, 16); rs0 += __shfl_xor(rs0, 32);
        rs1 += __shfl_xor(rs1, 16); rs1 += __shfl_xor(rs1, 32);
        l0r = l0r * al0 + rs0;
        l1r = l1r * al1 + rs1;
        m0r = mn0; m1r = mn1;

        // --- rescale O (redistribute al to this lane's O-rows g*4+j) ---
        float alr0[4], alr1[4];
#pragma unroll
        for (int j = 0; j < 4; ++j) {
            const int src = (l & 48) + g * 4 + j;
            alr0[j] = __shfl(al0, src);
            alr1[j] = __shfl(al1, src);
        }
#pragma unroll
        for (int c = 0; c < 4; ++c)
#pragma unroll
            for (int j = 0; j < 4; ++j) { o0[c][j] *= alr0[j]; o1[c][j] *= alr1[j]; }

        // --- O += P @ V (A = P from wave-private LDS, B = Vt) ---
#pragma unroll
        for (int kh = 0; kh < 2; ++kh) {
            const int pch = (kh * 4 + g) ^ (q16 & 7);
            const short8 p0f = *(const short8*)&Ps[0][w][q16 * 64 + pch * 8];
            const short8 p1f = *(const short8*)&Ps[1][w][q16 * 64 + pch * 8];
#pragma unroll
            for (int c = 0; c < 4; ++c) {
                const int vrow = c * 16 + q16;
                const int vch = (kh * 4 + g) ^ (vrow & 7);
                const short8 vf = *(const short8*)&Vts[vrow * 64 + vch * 8];
                o0[c] = mfma16(p0f, vf, o0[c]);
                o1[c] = mfma16(p1f, vf, o1[c]);
            }
        }
    }

    // --- epilogue: 1/l, diff combine, per-head LayerNorm, bf16 store ---
    const float inv0 = 1.f / l0r, inv1 = 1.f / l1r;
    float i0r[4], i1r[4];
#pragma unroll
    for (int j = 0; j < 4; ++j) {
        const int src = (l & 48) + g * 4 + j;
        i0r[j] = __shfl(inv0, src);
        i1r[j] = __shfl(inv1, src);
    }
    float lw[4], lb[4];
#pragma unroll
    for (int c = 0; c < 4; ++c) {
        lw[c] = lnw[h * 64 + c * 16 + q16];
        lb[c] = lnb[h * 64 + c * 16 + q16];
    }
#pragma unroll
    for (int j = 0; j < 4; ++j) {
        float hv[4];
        float sum = 0.f;
#pragma unroll
        for (int c = 0; c < 4; ++c) {
            hv[c] = o0[c][j] * i0r[j] - lamb * (o1[c][j] * i1r[j]);
            sum += hv[c];
        }
        sum += __shfl_xor(sum, 1); sum += __shfl_xor(sum, 2);
        sum += __shfl_xor(sum, 4); sum += __shfl_xor(sum, 8);
        const float mu = sum * (1.f / 64.f);
        float vs = 0.f;
#pragma unroll
        for (int c = 0; c < 4; ++c) { const float dd = hv[c] - mu; vs += dd * dd; }
        vs += __shfl_xor(vs, 1); vs += __shfl_xor(vs, 2);
        vs += __shfl_xor(vs, 4); vs += __shfl_xor(vs, 8);
        const float rstd = rsqrtf(vs * (1.f / 64.f) + 1e-5f);
        const int rowg = qt * 64 + w * 16 + g * 4 + j;
#pragma unroll
        for (int c = 0; c < 4; ++c) {
            const float nv = (hv[c] - mu) * rstd * lw[c] + lb[c];
            attnout[((size_t)(b * S_LEN + rowg)) * 1024 + h * 64 + c * 16 + q16] = (short)f2bf(nv);
        }
    }
}

// ---------------------------------------------------------------------------
extern "C" void kernel_launch(void* const* d_in, const int* in_sizes, int n_in,
                              void* d_out, int out_size, void* d_ws, size_t ws_size,
                              hipStream_t stream)
{
    (void)in_sizes; (void)n_in; (void)out_size; (void)ws_size;
    const float* x   = (const float*)d_in[0];
    const float* wq0 = (const float*)d_in[1];
    const float* wq1 = (const float*)d_in[2];
    const float* wk0 = (const float*)d_in[3];
    const float* wk1 = (const float*)d_in[4];
    const float* wv  = (const float*)d_in[5];
    const float* wo  = (const float*)d_in[6];
    const float* l0  = (const float*)d_in[7];
    const float* l1  = (const float*)d_in[8];
    const float* l2  = (const float*)d_in[9];
    const float* l3  = (const float*)d_in[10];
    const float* lnw = (const float*)d_in[11];
    const float* lnb = (const float*)d_in[12];
    float* out = (float*)d_out;
    short* ws = (short*)d_ws;

    const size_t M4 = (size_t)4 * 1024 * 1024;        // 4,194,304 elems
    short* xb    = ws;                                 // [4096][1024] bf16
    short* wtcat = ws + M4;                            // 6 x [1024][1024] bf16 (transposed)
    short* pbuf  = wtcat + (size_t)6 * 1024 * 1024;    // 5 x [b,h,s,dh] bf16
    short* atb   = pbuf + 5 * M4;                      // [4096][1024] bf16

    convert_x<<<4096, 256, 0, stream>>>(x, xb);
    transp_w<<<dim3(16, 16, 6), 256, 0, stream>>>(wq0, wq1, wk0, wk1, wv, wo, wtcat);
    gemm128<<<dim3(8, 32, 5), 256, 0, stream>>>(xb, wtcat, pbuf, nullptr, 0);
    diff_attn_mfma<<<dim3(32, 32), 256, 0, stream>>>(pbuf, l0, l1, l2, l3, lnw, lnb, atb);
    gemm128<<<dim3(8, 32, 1), 256, 0, stream>>>(atb, wtcat + (size_t)5 * 1024 * 1024,
                                                nullptr, out, 1);
}

// Round 3
// 227.846 us; speedup vs baseline: 12.3028x; 1.3979x over previous
//
#include <hip/hip_runtime.h>
#include <hip/hip_bf16.h>
#include <math.h>

#define S_LEN   2048
#define NH      16
#define DHEAD   64

typedef __attribute__((ext_vector_type(8))) short short8;
typedef __attribute__((ext_vector_type(4))) short short4v;
typedef __attribute__((ext_vector_type(4))) float f32x4;
typedef __attribute__((ext_vector_type(16))) float f32x16;
typedef __attribute__((ext_vector_type(4))) int int4v;

__device__ __forceinline__ f32x4 mfma16(short8 a, short8 b, f32x4 c) {
    return __builtin_amdgcn_mfma_f32_16x16x32_bf16(a, b, c, 0, 0, 0);
}
__device__ __forceinline__ f32x16 mfma32(short8 a, short8 b, f32x16 c) {
    return __builtin_amdgcn_mfma_f32_32x32x16_bf16(a, b, c, 0, 0, 0);
}

__device__ __forceinline__ unsigned short f2bf(float f) {
    unsigned u = __builtin_bit_cast(unsigned, f);
    u = (u + 0x7FFFu + ((u >> 16) & 1u)) >> 16;
    return (unsigned short)u;
}

// packs (lo, hi) fp32 -> one VGPR of 2 bf16 (RTE)
__device__ __forceinline__ int cvtpk(float lo, float hi) {
    int w;
    asm("v_cvt_pk_bf16_f32 %0, %1, %2" : "=v"(w) : "v"(lo), "v"(hi));
    return w;
}

#define GLL16(gp, lp) __builtin_amdgcn_global_load_lds( \
    (const __attribute__((address_space(1))) void*)(gp), \
    (__attribute__((address_space(3))) void*)(lp), 16, 0, 0)

// ---------------------------------------------------------------------------
// fp32 -> bf16 linear convert
// ---------------------------------------------------------------------------
__global__ __launch_bounds__(256)
void convert_x(const float* __restrict__ x, short* __restrict__ xb)
{
    const int idx = (blockIdx.x * 256 + threadIdx.x) * 4;
    typedef __attribute__((ext_vector_type(4))) float f4;
    f4 v = *(const f4*)&x[idx];
    short4v o;
    o[0] = (short)f2bf(v[0]); o[1] = (short)f2bf(v[1]);
    o[2] = (short)f2bf(v[2]); o[3] = (short)f2bf(v[3]);
    *(short4v*)&xb[idx] = o;
}

// ---------------------------------------------------------------------------
// transpose + convert weights: src fp32 [K=1024][N=1024] -> dst bf16 [N][K]
// wq0/wq1 (z<=1) are pre-scaled by 0.125*log2(e) so QK^T lands in the exp2
// domain with the 1/sqrt(DH) scale folded in for free.
// ---------------------------------------------------------------------------
__global__ __launch_bounds__(256)
void transp_w(const float* __restrict__ w0, const float* __restrict__ w1,
              const float* __restrict__ w2, const float* __restrict__ w3,
              const float* __restrict__ w4, const float* __restrict__ w5,
              short* __restrict__ wt)
{
    __shared__ float t[64][65];
    const int z = blockIdx.z;
    const float* src = (z == 0) ? w0 : (z == 1) ? w1 : (z == 2) ? w2
                     : (z == 3) ? w3 : (z == 4) ? w4 : w5;
    const float scale = (z <= 1) ? 0.125f * 1.44269504f : 1.0f;
    short* dst = wt + (size_t)z * 1024 * 1024;
    const int n0 = blockIdx.x * 64, k0 = blockIdx.y * 64;
    const int tid = threadIdx.x;
    const int c = tid & 63, rb = tid >> 6;
#pragma unroll
    for (int rr = 0; rr < 16; ++rr) {
        const int r = rr * 4 + rb;
        t[r][c] = src[(size_t)(k0 + r) * 1024 + n0 + c];
    }
    __syncthreads();
#pragma unroll
    for (int rr = 0; rr < 16; ++rr) {
        const int n = rr * 4 + rb;
        dst[(size_t)(n0 + n) * 1024 + k0 + c] = (short)f2bf(t[c][n] * scale);
    }
}

// ---------------------------------------------------------------------------
// bf16 MFMA GEMM: C[M x N] = A[M][1024] * Bt[N][1024]^T, 128x128 tile, BK=64.
// ---------------------------------------------------------------------------
__global__ __launch_bounds__(256)
void gemm128(const short* __restrict__ A, const short* __restrict__ Wt,
             short* __restrict__ outb, float* __restrict__ outf, int mode)
{
    __shared__ short As[128 * 64];
    __shared__ short Bs[128 * 64];
    const int tid = threadIdx.x;
    const int l = tid & 63, w = tid >> 6;
    const int wm = w >> 1, wn = w & 1;
    const int m0 = blockIdx.y * 128;
    const int n0 = blockIdx.x * 128;
    const short* Bt = Wt + (size_t)blockIdx.z * (1024 * 1024);
    const int srow = l >> 3;
    const int schunk = (l & 7) ^ srow;

    f32x4 acc[4][4];
#pragma unroll
    for (int i = 0; i < 4; ++i)
#pragma unroll
        for (int j = 0; j < 4; ++j)
            acc[i][j] = (f32x4){0.f, 0.f, 0.f, 0.f};

    for (int k0 = 0; k0 < 1024; k0 += 64) {
        __syncthreads();
#pragma unroll
        for (int ii = 0; ii < 4; ++ii) {
            const int i = w * 4 + ii;
            GLL16(A  + (size_t)(m0 + 8 * i + srow) * 1024 + k0 + schunk * 8, &As[i * 512]);
            GLL16(Bt + (size_t)(n0 + 8 * i + srow) * 1024 + k0 + schunk * 8, &Bs[i * 512]);
        }
        __syncthreads();
#pragma unroll
        for (int kh = 0; kh < 2; ++kh) {
            short8 af[4], bfr[4];
#pragma unroll
            for (int ft = 0; ft < 4; ++ft) {
                const int row = wm * 64 + ft * 16 + (l & 15);
                const int ch = (kh * 4 + (l >> 4)) ^ (row & 7);
                af[ft] = *(const short8*)&As[row * 64 + ch * 8];
            }
#pragma unroll
            for (int nt = 0; nt < 4; ++nt) {
                const int row = wn * 64 + nt * 16 + (l & 15);
                const int ch = (kh * 4 + (l >> 4)) ^ (row & 7);
                bfr[nt] = *(const short8*)&Bs[row * 64 + ch * 8];
            }
#pragma unroll
            for (int i = 0; i < 4; ++i)
#pragma unroll
                for (int j = 0; j < 4; ++j)
                    acc[i][j] = mfma16(af[i], bfr[j], acc[i][j]);
        }
    }

#pragma unroll
    for (int i = 0; i < 4; ++i)
#pragma unroll
        for (int j = 0; j < 4; ++j)
#pragma unroll
            for (int r = 0; r < 4; ++r) {
                const int m = m0 + wm * 64 + i * 16 + (l >> 4) * 4 + r;
                const int n = n0 + wn * 64 + j * 16 + (l & 15);
                const float v = acc[i][j][r];
                if (mode == 0) {
                    const int b = m >> 11, s = m & 2047;
                    const int h = n >> 6, dh = n & 63;
                    outb[(size_t)blockIdx.z * (4u * 1024 * 1024)
                         + (((size_t)(b * NH + h)) * S_LEN + s) * DHEAD + dh] = (short)f2bf(v);
                } else {
                    outf[(size_t)m * 1024 + n] = v;
                }
            }
}

// ---------------------------------------------------------------------------
// 32x32 MFMA flash differential attention.
// Block = 4 waves x 32 q-rows = 128 q-rows; KV tile 64. Swapped operands keep
// col = lane&31 = q for BOTH S^T = mfma(K,Q) and O^T = mfma(Vt,P^T), so all
// softmax/LN reductions are in-lane + one shfl_xor(32), rescale is
// lane-uniform, and P^T fragments are built in-register (cvt_pk + exchange).
// exp2-domain softmax (scale*log2e folded into wq), defer-max THR=8.
// ---------------------------------------------------------------------------
__global__ __launch_bounds__(256, 2)
void diff_attn_mfma(const short* __restrict__ pbuf,
                    const float* __restrict__ l0v, const float* __restrict__ l1v,
                    const float* __restrict__ l2v, const float* __restrict__ l3v,
                    const float* __restrict__ lnw, const float* __restrict__ lnb,
                    short* __restrict__ attnout)
{
    __shared__ short K0s[64 * 64];
    __shared__ short K1s[64 * 64];
    __shared__ short Vts[64 * 64];

    const int tid = threadIdx.x;
    const int l = tid & 63, w = tid >> 6;
    const int il = l & 31, hi = l >> 5;
    const int qt = 15 - (int)blockIdx.y;   // heavy tiles dispatched first
    const int bh = blockIdx.x;
    const int b = bh >> 4, h = bh & 15;
    const size_t MAT = (size_t)32 * S_LEN * DHEAD;
    const size_t hoff = (size_t)bh * S_LEN * DHEAD;
    const short* q0g = pbuf + 0 * MAT + hoff;
    const short* q1g = pbuf + 1 * MAT + hoff;
    const short* k0g = pbuf + 2 * MAT + hoff;
    const short* k1g = pbuf + 3 * MAT + hoff;
    const short* vg  = pbuf + 4 * MAT + hoff;

    const float slope2 = exp2f(-0.5f * (float)(h + 1)) * 1.44269504f;
    float d01 = 0.f, d23 = 0.f;
    for (int t = 0; t < DHEAD; ++t) { d01 += l0v[t] * l1v[t]; d23 += l2v[t] * l3v[t]; }
    const float lamb = (-__expf(d01) + 0.8f) + (-__expf(d23) + 0.8f);

    const int rg = qt * 128 + w * 32 + il;   // this lane's q-row (global)

    // Q fragments (B-operand): lane holds Q[q=il][dblk*16 + hi*8 .. +8]
    short8 qf0[4], qf1[4];
#pragma unroll
    for (int dblk = 0; dblk < 4; ++dblk) {
        qf0[dblk] = *(const short8*)&q0g[(size_t)rg * 64 + dblk * 16 + hi * 8];
        qf1[dblk] = *(const short8*)&q1g[(size_t)rg * 64 + dblk * 16 + hi * 8];
    }

    f32x16 ot0[2], ot1[2];
#pragma unroll
    for (int mb = 0; mb < 2; ++mb)
#pragma unroll
        for (int r = 0; r < 16; ++r) { ot0[mb][r] = 0.f; ot1[mb][r] = 0.f; }
    float m0r = -1e30f, m1r = -1e30f, l0r = 0.f, l1r = 0.f;

    const int srow = l >> 3;
    const int schunk = (l & 7) ^ srow;
    const int nkt = 2 * qt + 2;
    const int qw0 = qt * 128 + w * 32;
    const float fbias_hi = slope2 * (float)(4 * hi);

    for (int kt = 0; kt < nkt; ++kt) {
        __syncthreads();
        // --- stage K0, K1 (global_load_lds, source chunk-XOR, linear dest) ---
#pragma unroll
        for (int ii = 0; ii < 2; ++ii) {
            const int i = w * 2 + ii;
            GLL16(k0g + (size_t)(kt * 64 + 8 * i + srow) * 64 + schunk * 8, &K0s[i * 512]);
            GLL16(k1g + (size_t)(kt * 64 + 8 * i + srow) * 64 + schunk * 8, &K1s[i * 512]);
        }
        // --- stage V transposed: wave w owns d-rows [w*16, w*16+16) ---
        {
            const short* vp = vg + (size_t)(kt * 64 + l) * 64 + w * 16;
            short8 va = *(const short8*)vp;
            short8 vb2 = *(const short8*)(vp + 8);
#pragma unroll
            for (int e = 0; e < 16; ++e) {
                const short val = (e < 8) ? va[e] : vb2[e - 8];
                const int drow = w * 16 + e;
                const int csw = (l >> 3) ^ (drow & 7);
                Vts[drow * 64 + csw * 8 + (l & 7)] = val;
            }
        }
        __syncthreads();

        if (kt * 64 > qw0 + 31) continue;   // wave fully masked: staging only

        // --- S^T = K @ Q^T: D[kv][q], col = il = q ---
        f32x16 s0[2], s1[2];
#pragma unroll
        for (int kvb = 0; kvb < 2; ++kvb)
#pragma unroll
            for (int r = 0; r < 16; ++r) { s0[kvb][r] = 0.f; s1[kvb][r] = 0.f; }
#pragma unroll
        for (int dblk = 0; dblk < 4; ++dblk)
#pragma unroll
            for (int kvb = 0; kvb < 2; ++kvb) {
                const int rowA = kvb * 32 + il;
                const int ch = (dblk * 2 + hi) ^ (rowA & 7);
                const short8 k0f = *(const short8*)&K0s[rowA * 64 + ch * 8];
                const short8 k1f = *(const short8*)&K1s[rowA * 64 + ch * 8];
                s0[kvb] = mfma32(k0f, qf0[dblk], s0[kvb]);
                s1[kvb] = mfma32(k1f, qf1[dblk], s1[kvb]);
            }

        // --- ALiBi bias (exp2 domain), causal mask on diagonal tiles only ---
        const float Cit = slope2 * (float)(kt * 64 - rg) + fbias_hi;
#pragma unroll
        for (int kvb = 0; kvb < 2; ++kvb) {
            const float Cb = Cit + slope2 * (float)(kvb * 32);
#pragma unroll
            for (int r = 0; r < 16; ++r) {
                const int pat = (r & 3) + 8 * (r >> 2);
                const float bias = fmaf(slope2, (float)pat, Cb);
                s0[kvb][r] += bias;
                s1[kvb][r] += bias;
            }
        }
        if (kt * 64 + 63 > qw0) {           // diagonal: apply causal mask
            const int mth = rg - kt * 64;   // mask if kvoff > mth
#pragma unroll
            for (int kvb = 0; kvb < 2; ++kvb)
#pragma unroll
                for (int r = 0; r < 16; ++r) {
                    const int kvoff = kvb * 32 + (r & 3) + 8 * (r >> 2) + 4 * hi;
                    if (kvoff > mth) { s0[kvb][r] = -1e30f; s1[kvb][r] = -1e30f; }
                }
        }

        // --- row max: in-lane tree + xor32 ---
        float t0[16], t1[16];
#pragma unroll
        for (int r = 0; r < 16; ++r) {
            t0[r] = fmaxf(s0[0][r], s0[1][r]);
            t1[r] = fmaxf(s1[0][r], s1[1][r]);
        }
#pragma unroll
        for (int st = 8; st > 0; st >>= 1)
#pragma unroll
            for (int r = 0; r < st; ++r) {
                t0[r] = fmaxf(t0[r], t0[r + st]);
                t1[r] = fmaxf(t1[r], t1[r + st]);
            }
        const float pm0 = fmaxf(t0[0], __shfl_xor(t0[0], 32));
        const float pm1 = fmaxf(t1[0], __shfl_xor(t1[0], 32));

        // --- defer-max: rescale only if max grew by > 8 (log2 domain) ---
        const int need = (pm0 > m0r + 8.f) || (pm1 > m1r + 8.f);
        if (__any(need)) {
            const float mn0 = fmaxf(m0r, pm0), mn1 = fmaxf(m1r, pm1);
            const float al0 = exp2f(m0r - mn0), al1 = exp2f(m1r - mn1);
#pragma unroll
            for (int mb = 0; mb < 2; ++mb)
#pragma unroll
                for (int r = 0; r < 16; ++r) {
                    ot0[mb][r] *= al0;
                    ot1[mb][r] *= al1;
                }
            l0r *= al0; l1r *= al1;
            m0r = mn0; m1r = mn1;
        }

        // --- P = exp2(S - m), row sums ---
#pragma unroll
        for (int kvb = 0; kvb < 2; ++kvb)
#pragma unroll
            for (int r = 0; r < 16; ++r) {
                s0[kvb][r] = exp2f(s0[kvb][r] - m0r);
                s1[kvb][r] = exp2f(s1[kvb][r] - m1r);
            }
#pragma unroll
        for (int r = 0; r < 16; ++r) {
            t0[r] = s0[0][r] + s0[1][r];
            t1[r] = s1[0][r] + s1[1][r];
        }
#pragma unroll
        for (int st = 8; st > 0; st >>= 1)
#pragma unroll
            for (int r = 0; r < st; ++r) {
                t0[r] += t0[r + st];
                t1[r] += t1[r + st];
            }
        l0r += t0[0] + __shfl_xor(t0[0], 32);
        l1r += t1[0] + __shfl_xor(t1[0], 32);

        // --- build P^T fragments in-register (cvt_pk + cross-half exchange) ---
        short8 pa0[4], pa1[4];
#pragma unroll
        for (int ks = 0; ks < 4; ++ks) {
            const int kvb = ks >> 1, rb = (ks & 1) * 8;
            const int wa0 = cvtpk(s0[kvb][rb + 0], s0[kvb][rb + 1]);
            const int wb0 = cvtpk(s0[kvb][rb + 2], s0[kvb][rb + 3]);
            const int wc0 = cvtpk(s0[kvb][rb + 4], s0[kvb][rb + 5]);
            const int wd0 = cvtpk(s0[kvb][rb + 6], s0[kvb][rb + 7]);
            const int wa1 = cvtpk(s1[kvb][rb + 0], s1[kvb][rb + 1]);
            const int wb1 = cvtpk(s1[kvb][rb + 2], s1[kvb][rb + 3]);
            const int wc1 = cvtpk(s1[kvb][rb + 4], s1[kvb][rb + 5]);
            const int wd1 = cvtpk(s1[kvb][rb + 6], s1[kvb][rb + 7]);
            const int xa0 = __shfl_xor(wa0, 32), xb0 = __shfl_xor(wb0, 32);
            const int xc0 = __shfl_xor(wc0, 32), xd0 = __shfl_xor(wd0, 32);
            const int xa1 = __shfl_xor(wa1, 32), xb1 = __shfl_xor(wb1, 32);
            const int xc1 = __shfl_xor(wc1, 32), xd1 = __shfl_xor(wd1, 32);
            union { int4v wi; short8 sv; } u0, u1;
            u0.wi[0] = hi ? xc0 : wa0;
            u0.wi[1] = hi ? xd0 : wb0;
            u0.wi[2] = hi ? wc0 : xa0;
            u0.wi[3] = hi ? wd0 : xb0;
            u1.wi[0] = hi ? xc1 : wa1;
            u1.wi[1] = hi ? xd1 : wb1;
            u1.wi[2] = hi ? wc1 : xa1;
            u1.wi[3] = hi ? wd1 : xb1;
            pa0[ks] = u0.sv;
            pa1[ks] = u1.sv;
        }

        // --- O^T += Vt @ P^T: D[d][q], col = il = q ---
#pragma unroll
        for (int mb = 0; mb < 2; ++mb)
#pragma unroll
            for (int ks = 0; ks < 4; ++ks) {
                const int rowV = mb * 32 + il;
                const int ch = (ks * 2 + hi) ^ (rowV & 7);
                const short8 vf = *(const short8*)&Vts[rowV * 64 + ch * 8];
                ot0[mb] = mfma32(vf, pa0[ks], ot0[mb]);
                ot1[mb] = mfma32(vf, pa1[ks], ot1[mb]);
            }
    }

    // --- epilogue: 1/l, diff combine, per-head LayerNorm (in-lane + xor32) ---
    const float inv0 = 1.f / l0r, inv1 = 1.f / l1r;
    float hv[2][16];
    float tsum[16];
#pragma unroll
    for (int r = 0; r < 16; ++r) {
        hv[0][r] = ot0[0][r] * inv0 - lamb * (ot1[0][r] * inv1);
        hv[1][r] = ot0[1][r] * inv0 - lamb * (ot1[1][r] * inv1);
        tsum[r] = hv[0][r] + hv[1][r];
    }
#pragma unroll
    for (int st = 8; st > 0; st >>= 1)
#pragma unroll
        for (int r = 0; r < st; ++r) tsum[r] += tsum[r + st];
    const float sum = tsum[0] + __shfl_xor(tsum[0], 32);
    const float mu = sum * (1.f / 64.f);
#pragma unroll
    for (int r = 0; r < 16; ++r) {
        const float d0 = hv[0][r] - mu, d1 = hv[1][r] - mu;
        tsum[r] = d0 * d0 + d1 * d1;
    }
#pragma unroll
    for (int st = 8; st > 0; st >>= 1)
#pragma unroll
        for (int r = 0; r < st; ++r) tsum[r] += tsum[r + st];
    const float vsum = tsum[0] + __shfl_xor(tsum[0], 32);
    const float rstd = rsqrtf(vsum * (1.f / 64.f) + 1e-5f);

#pragma unroll
    for (int mb = 0; mb < 2; ++mb)
#pragma unroll
        for (int r = 0; r < 16; ++r) {
            const int d = mb * 32 + (r & 3) + 8 * (r >> 2) + 4 * hi;
            hv[mb][r] = (hv[mb][r] - mu) * rstd * lnw[h * 64 + d] + lnb[h * 64 + d];
        }

    short* orow = attnout + ((size_t)(b * S_LEN + rg)) * 1024 + h * 64;
#pragma unroll
    for (int mb = 0; mb < 2; ++mb)
#pragma unroll
        for (int a = 0; a < 4; ++a) {
            union { int wi[2]; short4v sv; } st;
            st.wi[0] = cvtpk(hv[mb][4 * a + 0], hv[mb][4 * a + 1]);
            st.wi[1] = cvtpk(hv[mb][4 * a + 2], hv[mb][4 * a + 3]);
            *(short4v*)&orow[mb * 32 + 8 * a + 4 * hi] = st.sv;
        }
}

// ---------------------------------------------------------------------------
extern "C" void kernel_launch(void* const* d_in, const int* in_sizes, int n_in,
                              void* d_out, int out_size, void* d_ws, size_t ws_size,
                              hipStream_t stream)
{
    (void)in_sizes; (void)n_in; (void)out_size; (void)ws_size;
    const float* x   = (const float*)d_in[0];
    const float* wq0 = (const float*)d_in[1];
    const float* wq1 = (const float*)d_in[2];
    const float* wk0 = (const float*)d_in[3];
    const float* wk1 = (const float*)d_in[4];
    const float* wv  = (const float*)d_in[5];
    const float* wo  = (const float*)d_in[6];
    const float* l0  = (const float*)d_in[7];
    const float* l1  = (const float*)d_in[8];
    const float* l2  = (const float*)d_in[9];
    const float* l3  = (const float*)d_in[10];
    const float* lnw = (const float*)d_in[11];
    const float* lnb = (const float*)d_in[12];
    float* out = (float*)d_out;
    short* ws = (short*)d_ws;

    const size_t M4 = (size_t)4 * 1024 * 1024;
    short* xb    = ws;                                 // [4096][1024] bf16
    short* wtcat = ws + M4;                            // 6 x [1024][1024] bf16 (transposed)
    short* pbuf  = wtcat + (size_t)6 * 1024 * 1024;    // 5 x [b,h,s,dh] bf16
    short* atb   = pbuf + 5 * M4;                      // [4096][1024] bf16

    convert_x<<<4096, 256, 0, stream>>>(x, xb);
    transp_w<<<dim3(16, 16, 6), 256, 0, stream>>>(wq0, wq1, wk0, wk1, wv, wo, wtcat);
    gemm128<<<dim3(8, 32, 5), 256, 0, stream>>>(xb, wtcat, pbuf, nullptr, 0);
    diff_attn_mfma<<<dim3(32, 16), 256, 0, stream>>>(pbuf, l0, l1, l2, l3, lnw, lnb, atb);
    gemm128<<<dim3(8, 32, 1), 256, 0, stream>>>(atb, wtcat + (size_t)5 * 1024 * 1024,
                                                nullptr, out, 1);
}

// Round 4
// 191.239 us; speedup vs baseline: 14.6578x; 1.1914x over previous
//
#include <hip/hip_runtime.h>
#include <hip/hip_bf16.h>
#include <math.h>

#define S_LEN   2048
#define NH      16
#define DHEAD   64

typedef __attribute__((ext_vector_type(8))) short short8;
typedef __attribute__((ext_vector_type(4))) short short4v;
typedef __attribute__((ext_vector_type(4))) float f32x4;
typedef __attribute__((ext_vector_type(16))) float f32x16;
typedef __attribute__((ext_vector_type(4))) int int4v;

__device__ __forceinline__ f32x4 mfma16(short8 a, short8 b, f32x4 c) {
    return __builtin_amdgcn_mfma_f32_16x16x32_bf16(a, b, c, 0, 0, 0);
}
__device__ __forceinline__ f32x16 mfma32(short8 a, short8 b, f32x16 c) {
    return __builtin_amdgcn_mfma_f32_32x32x16_bf16(a, b, c, 0, 0, 0);
}

__device__ __forceinline__ unsigned short f2bf(float f) {
    unsigned u = __builtin_bit_cast(unsigned, f);
    u = (u + 0x7FFFu + ((u >> 16) & 1u)) >> 16;
    return (unsigned short)u;
}

// packs (lo, hi) fp32 -> one VGPR of 2 bf16 (RTE)
__device__ __forceinline__ int cvtpk(float lo, float hi) {
    int w;
    asm("v_cvt_pk_bf16_f32 %0, %1, %2" : "=v"(w) : "v"(lo), "v"(hi));
    return w;
}

// mutual half-swap: a.hi <-> b.lo  (a becomes {a.lo | b.lo}, b becomes {a.hi | b.hi})
__device__ __forceinline__ void pl32swap(int& a, int& b) {
    asm("v_permlane32_swap_b32 %0, %1" : "+v"(a), "+v"(b));
}

#define GLL16(gp, lp) __builtin_amdgcn_global_load_lds( \
    (const __attribute__((address_space(1))) void*)(gp), \
    (__attribute__((address_space(3))) void*)(lp), 16, 0, 0)

// ---------------------------------------------------------------------------
// fp32 -> bf16 linear convert
// ---------------------------------------------------------------------------
__global__ __launch_bounds__(256)
void convert_x(const float* __restrict__ x, short* __restrict__ xb)
{
    const int idx = (blockIdx.x * 256 + threadIdx.x) * 4;
    typedef __attribute__((ext_vector_type(4))) float f4;
    f4 v = *(const f4*)&x[idx];
    short4v o;
    o[0] = (short)f2bf(v[0]); o[1] = (short)f2bf(v[1]);
    o[2] = (short)f2bf(v[2]); o[3] = (short)f2bf(v[3]);
    *(short4v*)&xb[idx] = o;
}

// ---------------------------------------------------------------------------
// transpose + convert weights: src fp32 [K=1024][N=1024] -> dst bf16 [N][K]
// wq0/wq1 (z<=1) pre-scaled by 0.125*log2(e) (exp2-domain softmax).
// ---------------------------------------------------------------------------
__global__ __launch_bounds__(256)
void transp_w(const float* __restrict__ w0, const float* __restrict__ w1,
              const float* __restrict__ w2, const float* __restrict__ w3,
              const float* __restrict__ w4, const float* __restrict__ w5,
              short* __restrict__ wt)
{
    __shared__ float t[64][65];
    const int z = blockIdx.z;
    const float* src = (z == 0) ? w0 : (z == 1) ? w1 : (z == 2) ? w2
                     : (z == 3) ? w3 : (z == 4) ? w4 : w5;
    const float scale = (z <= 1) ? 0.125f * 1.44269504f : 1.0f;
    short* dst = wt + (size_t)z * 1024 * 1024;
    const int n0 = blockIdx.x * 64, k0 = blockIdx.y * 64;
    const int tid = threadIdx.x;
    const int c = tid & 63, rb = tid >> 6;
#pragma unroll
    for (int rr = 0; rr < 16; ++rr) {
        const int r = rr * 4 + rb;
        t[r][c] = src[(size_t)(k0 + r) * 1024 + n0 + c];
    }
    __syncthreads();
#pragma unroll
    for (int rr = 0; rr < 16; ++rr) {
        const int n = rr * 4 + rb;
        dst[(size_t)(n0 + n) * 1024 + k0 + c] = (short)f2bf(t[c][n] * scale);
    }
}

// ---------------------------------------------------------------------------
// transpose V: bf16 [bh][s=2048][dh=64] -> [bh][dh=64][s=2048]
// ---------------------------------------------------------------------------
__global__ __launch_bounds__(256)
void transp_v(const short* __restrict__ vsrc, short* __restrict__ vdst)
{
    __shared__ short t[64][68];
    const int bh = blockIdx.y;
    const int s0 = blockIdx.x * 64;
    const int tid = threadIdx.x;
    const int c = tid & 63, rb = tid >> 6;
    const size_t base = (size_t)bh * S_LEN * DHEAD;
#pragma unroll
    for (int rr = 0; rr < 16; ++rr) {
        const int r = rr * 4 + rb;
        t[r][c] = vsrc[base + (size_t)(s0 + r) * 64 + c];
    }
    __syncthreads();
#pragma unroll
    for (int rr = 0; rr < 16; ++rr) {
        const int d = rr * 4 + rb;
        vdst[base + (size_t)d * S_LEN + s0 + c] = t[c][d];
    }
}

// ---------------------------------------------------------------------------
// bf16 MFMA GEMM: C[M x N] = A[M][1024] * Bt[N][1024]^T, 128x128 tile, BK=64.
// ---------------------------------------------------------------------------
__global__ __launch_bounds__(256)
void gemm128(const short* __restrict__ A, const short* __restrict__ Wt,
             short* __restrict__ outb, float* __restrict__ outf, int mode)
{
    __shared__ short As[128 * 64];
    __shared__ short Bs[128 * 64];
    const int tid = threadIdx.x;
    const int l = tid & 63, w = tid >> 6;
    const int wm = w >> 1, wn = w & 1;
    const int m0 = blockIdx.y * 128;
    const int n0 = blockIdx.x * 128;
    const short* Bt = Wt + (size_t)blockIdx.z * (1024 * 1024);
    const int srow = l >> 3;
    const int schunk = (l & 7) ^ srow;

    f32x4 acc[4][4];
#pragma unroll
    for (int i = 0; i < 4; ++i)
#pragma unroll
        for (int j = 0; j < 4; ++j)
            acc[i][j] = (f32x4){0.f, 0.f, 0.f, 0.f};

    for (int k0 = 0; k0 < 1024; k0 += 64) {
        __syncthreads();
#pragma unroll
        for (int ii = 0; ii < 4; ++ii) {
            const int i = w * 4 + ii;
            GLL16(A  + (size_t)(m0 + 8 * i + srow) * 1024 + k0 + schunk * 8, &As[i * 512]);
            GLL16(Bt + (size_t)(n0 + 8 * i + srow) * 1024 + k0 + schunk * 8, &Bs[i * 512]);
        }
        __syncthreads();
#pragma unroll
        for (int kh = 0; kh < 2; ++kh) {
            short8 af[4], bfr[4];
#pragma unroll
            for (int ft = 0; ft < 4; ++ft) {
                const int row = wm * 64 + ft * 16 + (l & 15);
                const int ch = (kh * 4 + (l >> 4)) ^ (row & 7);
                af[ft] = *(const short8*)&As[row * 64 + ch * 8];
            }
#pragma unroll
            for (int nt = 0; nt < 4; ++nt) {
                const int row = wn * 64 + nt * 16 + (l & 15);
                const int ch = (kh * 4 + (l >> 4)) ^ (row & 7);
                bfr[nt] = *(const short8*)&Bs[row * 64 + ch * 8];
            }
#pragma unroll
            for (int i = 0; i < 4; ++i)
#pragma unroll
                for (int j = 0; j < 4; ++j)
                    acc[i][j] = mfma16(af[i], bfr[j], acc[i][j]);
        }
    }

#pragma unroll
    for (int i = 0; i < 4; ++i)
#pragma unroll
        for (int j = 0; j < 4; ++j)
#pragma unroll
            for (int r = 0; r < 4; ++r) {
                const int m = m0 + wm * 64 + i * 16 + (l >> 4) * 4 + r;
                const int n = n0 + wn * 64 + j * 16 + (l & 15);
                const float v = acc[i][j][r];
                if (mode == 0) {
                    const int b = m >> 11, s = m & 2047;
                    const int h = n >> 6, dh = n & 63;
                    outb[(size_t)blockIdx.z * (4u * 1024 * 1024)
                         + (((size_t)(b * NH + h)) * S_LEN + s) * DHEAD + dh] = (short)f2bf(v);
                } else {
                    outf[(size_t)m * 1024 + n] = v;
                }
            }
}

// ---------------------------------------------------------------------------
// 32x32 MFMA flash differential attention, double-buffered staging.
// Loop: STAGE(kt+1) -> vmcnt(6) -> s_barrier -> compute(kt) -> s_barrier.
// Bias - running_max folded into MFMA C-init (relative-score domain).
// P^T fragments built in-register via cvt_pk + v_permlane32_swap.
// ---------------------------------------------------------------------------
__global__ __launch_bounds__(256, 2)
void diff_attn_mfma(const short* __restrict__ pbuf, const short* __restrict__ vtb,
                    const float* __restrict__ l0v, const float* __restrict__ l1v,
                    const float* __restrict__ l2v, const float* __restrict__ l3v,
                    const float* __restrict__ lnw, const float* __restrict__ lnb,
                    short* __restrict__ attnout)
{
    __shared__ short Ks[2][3][64 * 64];   // [buf][K0,K1,Vt] = 48 KB

    const int tid = threadIdx.x;
    const int l = tid & 63, w = tid >> 6;
    const int il = l & 31, hi = l >> 5;
    const int qt = 15 - (int)blockIdx.y;   // heavy tiles dispatched first
    const int bh = blockIdx.x;
    const int b = bh >> 4, h = bh & 15;
    const size_t MAT = (size_t)32 * S_LEN * DHEAD;
    const size_t hoff = (size_t)bh * S_LEN * DHEAD;
    const short* q0g = pbuf + 0 * MAT + hoff;
    const short* q1g = pbuf + 1 * MAT + hoff;
    const short* k0g = pbuf + 2 * MAT + hoff;
    const short* k1g = pbuf + 3 * MAT + hoff;
    const short* vtg = vtb + hoff;          // [dh=64][s=2048]

    const float slope2 = exp2f(-0.5f * (float)(h + 1)) * 1.44269504f;
    float d01 = 0.f, d23 = 0.f;
    for (int t = 0; t < DHEAD; ++t) { d01 += l0v[t] * l1v[t]; d23 += l2v[t] * l3v[t]; }
    const float lamb = (-__expf(d01) + 0.8f) + (-__expf(d23) + 0.8f);

    const int rg = qt * 128 + w * 32 + il;   // this lane's q-row (global)

    short8 qf0[4], qf1[4];
#pragma unroll
    for (int dblk = 0; dblk < 4; ++dblk) {
        qf0[dblk] = *(const short8*)&q0g[(size_t)rg * 64 + dblk * 16 + hi * 8];
        qf1[dblk] = *(const short8*)&q1g[(size_t)rg * 64 + dblk * 16 + hi * 8];
    }

    f32x16 ot0[2], ot1[2];
#pragma unroll
    for (int mb = 0; mb < 2; ++mb)
#pragma unroll
        for (int r = 0; r < 16; ++r) { ot0[mb][r] = 0.f; ot1[mb][r] = 0.f; }
    float m0r = -100000.f, m1r = -100000.f, l0r = 0.f, l1r = 0.f;

    const int srow = l >> 3;
    const int schunk = (l & 7) ^ srow;
    const int nkt = 2 * qt + 2;
    const int qw0 = qt * 128 + w * 32;

#define STAGE(kt_, bi_) do {                                                        \
    _Pragma("unroll")                                                               \
    for (int ii = 0; ii < 2; ++ii) {                                                \
        const int i_ = w * 2 + ii;                                                  \
        GLL16(k0g + (size_t)((kt_) * 64 + 8 * i_ + srow) * 64 + schunk * 8,         \
              &Ks[bi_][0][i_ * 512]);                                               \
        GLL16(k1g + (size_t)((kt_) * 64 + 8 * i_ + srow) * 64 + schunk * 8,         \
              &Ks[bi_][1][i_ * 512]);                                               \
        GLL16(vtg + (size_t)(8 * i_ + srow) * S_LEN + (kt_) * 64 + schunk * 8,      \
              &Ks[bi_][2][i_ * 512]);                                               \
    }                                                                               \
} while (0)

    STAGE(0, 0);

    for (int kt = 0; kt < nkt; ++kt) {
        const int cur = kt & 1;
        if (kt + 1 < nkt) {
            STAGE(kt + 1, cur ^ 1);
            asm volatile("s_waitcnt vmcnt(6)" ::: "memory");
        } else {
            asm volatile("s_waitcnt vmcnt(0)" ::: "memory");
        }
        __builtin_amdgcn_s_barrier();

        if (kt * 64 <= qw0 + 31) {
            // --- C-init = alibi_bias - m  (relative-score domain) ---
            f32x16 s0[2], s1[2];
            const float cb0 = slope2 * (float)(kt * 64 + 4 * hi - rg) - m0r;
            const float dm = m0r - m1r;
#pragma unroll
            for (int kvb = 0; kvb < 2; ++kvb) {
                const float cb = cb0 + slope2 * (float)(kvb * 32);
#pragma unroll
                for (int r = 0; r < 16; ++r) {
                    const float pat = (float)((r & 3) + 8 * (r >> 2));
                    s0[kvb][r] = fmaf(slope2, pat, cb);
                    s1[kvb][r] = s0[kvb][r] + dm;
                }
            }

            // --- S^T = K @ Q^T (accumulating onto bias-m init) ---
#pragma unroll
            for (int dblk = 0; dblk < 4; ++dblk)
#pragma unroll
                for (int kvb = 0; kvb < 2; ++kvb) {
                    const int rowA = kvb * 32 + il;
                    const int ch = (dblk * 2 + hi) ^ (rowA & 7);
                    const short8 k0f = *(const short8*)&Ks[cur][0][rowA * 64 + ch * 8];
                    const short8 k1f = *(const short8*)&Ks[cur][1][rowA * 64 + ch * 8];
                    s0[kvb] = mfma32(k0f, qf0[dblk], s0[kvb]);
                    s1[kvb] = mfma32(k1f, qf1[dblk], s1[kvb]);
                }

            // --- causal mask on diagonal tiles only ---
            if (kt * 64 + 63 > qw0) {
                const int mth = rg - kt * 64;
#pragma unroll
                for (int kvb = 0; kvb < 2; ++kvb)
#pragma unroll
                    for (int r = 0; r < 16; ++r) {
                        const int kvoff = kvb * 32 + (r & 3) + 8 * (r >> 2) + 4 * hi;
                        if (kvoff > mth) { s0[kvb][r] = -1e30f; s1[kvb][r] = -1e30f; }
                    }
            }

            // --- row max (relative): fold + tree + cross-half ---
            float t0[8], t1[8];
#pragma unroll
            for (int r = 0; r < 8; ++r) {
                t0[r] = fmaxf(fmaxf(s0[0][r], s0[0][r + 8]), fmaxf(s0[1][r], s0[1][r + 8]));
                t1[r] = fmaxf(fmaxf(s1[0][r], s1[0][r + 8]), fmaxf(s1[1][r], s1[1][r + 8]));
            }
            float pm0 = fmaxf(fmaxf(fmaxf(t0[0], t0[1]), fmaxf(t0[2], t0[3])),
                              fmaxf(fmaxf(t0[4], t0[5]), fmaxf(t0[6], t0[7])));
            float pm1 = fmaxf(fmaxf(fmaxf(t1[0], t1[1]), fmaxf(t1[2], t1[3])),
                              fmaxf(fmaxf(t1[4], t1[5]), fmaxf(t1[6], t1[7])));
            pm0 = fmaxf(pm0, __shfl_xor(pm0, 32));
            pm1 = fmaxf(pm1, __shfl_xor(pm1, 32));

            // --- defer-max: rescale only if relative max grew past THR=8 ---
            if (__any(pm0 > 8.f || pm1 > 8.f)) {
                const float d0 = fmaxf(pm0, 0.f), d1 = fmaxf(pm1, 0.f);
                const float sc0 = __builtin_amdgcn_exp2f(-d0);
                const float sc1 = __builtin_amdgcn_exp2f(-d1);
#pragma unroll
                for (int mb = 0; mb < 2; ++mb)
#pragma unroll
                    for (int r = 0; r < 16; ++r) {
                        ot0[mb][r] *= sc0;
                        ot1[mb][r] *= sc1;
                    }
                l0r *= sc0; l1r *= sc1;
                m0r += d0; m1r += d1;
#pragma unroll
                for (int kvb = 0; kvb < 2; ++kvb)
#pragma unroll
                    for (int r = 0; r < 16; ++r) {
                        s0[kvb][r] -= d0;
                        s1[kvb][r] -= d1;
                    }
            }

            // --- P = exp2(rel), row sums ---
#pragma unroll
            for (int kvb = 0; kvb < 2; ++kvb)
#pragma unroll
                for (int r = 0; r < 16; ++r) {
                    s0[kvb][r] = __builtin_amdgcn_exp2f(s0[kvb][r]);
                    s1[kvb][r] = __builtin_amdgcn_exp2f(s1[kvb][r]);
                }
            float u0[8], u1[8];
#pragma unroll
            for (int r = 0; r < 8; ++r) {
                u0[r] = (s0[0][r] + s0[0][r + 8]) + (s0[1][r] + s0[1][r + 8]);
                u1[r] = (s1[0][r] + s1[0][r + 8]) + (s1[1][r] + s1[1][r + 8]);
            }
            float rs0 = ((u0[0] + u0[1]) + (u0[2] + u0[3])) + ((u0[4] + u0[5]) + (u0[6] + u0[7]));
            float rs1 = ((u1[0] + u1[1]) + (u1[2] + u1[3])) + ((u1[4] + u1[5]) + (u1[6] + u1[7]));
            rs0 += __shfl_xor(rs0, 32);
            rs1 += __shfl_xor(rs1, 32);
            l0r += rs0; l1r += rs1;

            // --- P^T fragments: cvt_pk + permlane32_swap (no LDS, no bpermute) ---
            short8 pa0[4], pa1[4];
#pragma unroll
            for (int ks = 0; ks < 4; ++ks) {
                const int kvb = ks >> 1, rb = (ks & 1) * 8;
                int wa0 = cvtpk(s0[kvb][rb + 0], s0[kvb][rb + 1]);
                int wb0 = cvtpk(s0[kvb][rb + 2], s0[kvb][rb + 3]);
                int wc0 = cvtpk(s0[kvb][rb + 4], s0[kvb][rb + 5]);
                int wd0 = cvtpk(s0[kvb][rb + 6], s0[kvb][rb + 7]);
                pl32swap(wa0, wc0);
                pl32swap(wb0, wd0);
                int wa1 = cvtpk(s1[kvb][rb + 0], s1[kvb][rb + 1]);
                int wb1 = cvtpk(s1[kvb][rb + 2], s1[kvb][rb + 3]);
                int wc1 = cvtpk(s1[kvb][rb + 4], s1[kvb][rb + 5]);
                int wd1 = cvtpk(s1[kvb][rb + 6], s1[kvb][rb + 7]);
                pl32swap(wa1, wc1);
                pl32swap(wb1, wd1);
                union { int4v wi; short8 sv; } u0u, u1u;
                u0u.wi[0] = wa0; u0u.wi[1] = wb0; u0u.wi[2] = wc0; u0u.wi[3] = wd0;
                u1u.wi[0] = wa1; u1u.wi[1] = wb1; u1u.wi[2] = wc1; u1u.wi[3] = wd1;
                pa0[ks] = u0u.sv;
                pa1[ks] = u1u.sv;
            }

            // --- O^T += Vt @ P^T ---
#pragma unroll
            for (int mb = 0; mb < 2; ++mb)
#pragma unroll
                for (int ks = 0; ks < 4; ++ks) {
                    const int rowV = mb * 32 + il;
                    const int ch = (ks * 2 + hi) ^ (rowV & 7);
                    const short8 vf = *(const short8*)&Ks[cur][2][rowV * 64 + ch * 8];
                    ot0[mb] = mfma32(vf, pa0[ks], ot0[mb]);
                    ot1[mb] = mfma32(vf, pa1[ks], ot1[mb]);
                }
        }
        __builtin_amdgcn_s_barrier();
    }
#undef STAGE

    // --- epilogue: 1/l, diff combine, per-head LayerNorm (in-lane + xor32) ---
    const float inv0 = 1.f / l0r, inv1 = 1.f / l1r;
    float hv[2][16];
    float tsum[16];
#pragma unroll
    for (int r = 0; r < 16; ++r) {
        hv[0][r] = ot0[0][r] * inv0 - lamb * (ot1[0][r] * inv1);
        hv[1][r] = ot0[1][r] * inv0 - lamb * (ot1[1][r] * inv1);
        tsum[r] = hv[0][r] + hv[1][r];
    }
#pragma unroll
    for (int st = 8; st > 0; st >>= 1)
#pragma unroll
        for (int r = 0; r < st; ++r) tsum[r] += tsum[r + st];
    const float sum = tsum[0] + __shfl_xor(tsum[0], 32);
    const float mu = sum * (1.f / 64.f);
#pragma unroll
    for (int r = 0; r < 16; ++r) {
        const float dd0 = hv[0][r] - mu, dd1 = hv[1][r] - mu;
        tsum[r] = dd0 * dd0 + dd1 * dd1;
    }
#pragma unroll
    for (int st = 8; st > 0; st >>= 1)
#pragma unroll
        for (int r = 0; r < st; ++r) tsum[r] += tsum[r + st];
    const float vsum = tsum[0] + __shfl_xor(tsum[0], 32);
    const float rstd = rsqrtf(vsum * (1.f / 64.f) + 1e-5f);

#pragma unroll
    for (int mb = 0; mb < 2; ++mb)
#pragma unroll
        for (int r = 0; r < 16; ++r) {
            const int d = mb * 32 + (r & 3) + 8 * (r >> 2) + 4 * hi;
            hv[mb][r] = (hv[mb][r] - mu) * rstd * lnw[h * 64 + d] + lnb[h * 64 + d];
        }

    short* orow = attnout + ((size_t)(b * S_LEN + rg)) * 1024 + h * 64;
#pragma unroll
    for (int mb = 0; mb < 2; ++mb)
#pragma unroll
        for (int a = 0; a < 4; ++a) {
            union { int wi[2]; short4v sv; } st;
            st.wi[0] = cvtpk(hv[mb][4 * a + 0], hv[mb][4 * a + 1]);
            st.wi[1] = cvtpk(hv[mb][4 * a + 2], hv[mb][4 * a + 3]);
            *(short4v*)&orow[mb * 32 + 8 * a + 4 * hi] = st.sv;
        }
}

// ---------------------------------------------------------------------------
extern "C" void kernel_launch(void* const* d_in, const int* in_sizes, int n_in,
                              void* d_out, int out_size, void* d_ws, size_t ws_size,
                              hipStream_t stream)
{
    (void)in_sizes; (void)n_in; (void)out_size; (void)ws_size;
    const float* x   = (const float*)d_in[0];
    const float* wq0 = (const float*)d_in[1];
    const float* wq1 = (const float*)d_in[2];
    const float* wk0 = (const float*)d_in[3];
    const float* wk1 = (const float*)d_in[4];
    const float* wv  = (const float*)d_in[5];
    const float* wo  = (const float*)d_in[6];
    const float* l0  = (const float*)d_in[7];
    const float* l1  = (const float*)d_in[8];
    const float* l2  = (const float*)d_in[9];
    const float* l3  = (const float*)d_in[10];
    const float* lnw = (const float*)d_in[11];
    const float* lnb = (const float*)d_in[12];
    float* out = (float*)d_out;
    short* ws = (short*)d_ws;

    const size_t M4 = (size_t)4 * 1024 * 1024;
    short* xb    = ws;                                 // [4096][1024] bf16 (dead after proj)
    short* wtcat = ws + M4;                            // 6 x [1024][1024] bf16 (transposed)
    short* pbuf  = wtcat + (size_t)6 * 1024 * 1024;    // 5 x [b,h,s,dh] bf16
    short* atb   = pbuf + 5 * M4;                      // [4096][1024] bf16
    short* vtb   = xb;                                 // aliases xb: [bh][dh][s] bf16

    convert_x<<<4096, 256, 0, stream>>>(x, xb);
    transp_w<<<dim3(16, 16, 6), 256, 0, stream>>>(wq0, wq1, wk0, wk1, wv, wo, wtcat);
    gemm128<<<dim3(8, 32, 5), 256, 0, stream>>>(xb, wtcat, pbuf, nullptr, 0);
    transp_v<<<dim3(32, 32), 256, 0, stream>>>(pbuf + 4 * M4, vtb);
    diff_attn_mfma<<<dim3(32, 16), 256, 0, stream>>>(pbuf, vtb,
                                                     l0, l1, l2, l3, lnw, lnb, atb);
    gemm128<<<dim3(8, 32, 1), 256, 0, stream>>>(atb, wtcat + (size_t)5 * 1024 * 1024,
                                                nullptr, out, 1);
}